// Round 4
// baseline (242.522 us; speedup 1.0000x reference)
//
#include <hip/hip_runtime.h>

#define BINS   10
#define CSHIFT 26
#define QMASK  0x03FFFFFFu
#define QSCALE 2097152.0f        // 2^21 quanta per loss unit
#define QLN2   1453635.25f       // ln2 * 2^21: q = log2(1+em) * QLN2

// ws layout (all CUMULATIVE over bins): float qsum[10] @ byte 0 (loss units),
// unsigned cnt[10] @ byte 64. Re-poisoned 0xAA each replay -> zero each launch.

__global__ void ghm_zero_ws(unsigned* ws) {
    if (threadIdx.x < 32) ws[threadIdx.x] = 0u;
}

// d-space bin edges: bin b <=> D[b+1] < d <= D[b], D[b] = ln(20/b - 1), D[10]=0.
// Cumulative acc A[b] sums over {d > D[b+1]}; A[9] = all valid (d > 0).
__device__ __forceinline__ void proc1(float o0, float o1, int t, unsigned* A) {
    const float Th[BINS] = {                   // Th[b] = D[b+1]
        2.9444390f, 2.1972246f, 1.7346011f, 1.3862944f, 1.0986123f,
        0.8472979f, 0.6190392f, 0.4054651f, 0.2006707f, 0.0f };
    float s = o0 - o1;
    float d = __int_as_float(__float_as_int(s) ^ (t << 31));  // target - other
    // packed val = (1<<26) + round(loss * 2^21), loss = log1p(exp(-d))
    float em   = __expf(-d);
    float onep = 1.0f + em;
    float qf   = fmaf(__log2f(onep), QLN2, 0.5f);
    unsigned val = (unsigned)qf + (1u << CSHIFT);  // garbage if d<=0: fully masked below
    #pragma unroll
    for (int b = 0; b < BINS; ++b)
        A[b] += (d > Th[b]) ? val : 0u;            // v_cmp + v_cndmask + v_add
}

__device__ __forceinline__ void proc4(float4 a, float4 b, int4 t, unsigned* A) {
    proc1(a.x, a.y, t.x, A);
    proc1(a.z, a.w, t.y, A);
    proc1(b.x, b.y, t.z, A);
    proc1(b.z, b.w, t.w, A);
}

__global__ __launch_bounds__(256, 4)
void ghm_main(const float* __restrict__ outs,   // [n,2]
              const int*   __restrict__ tgt,    // [n]
              float*       __restrict__ ws_q,   // cumulative loss sums
              unsigned*    __restrict__ ws_c,   // cumulative counts
              int n) {
    unsigned A[BINS];
    #pragma unroll
    for (int b = 0; b < BINS; ++b) A[b] = 0u;

    const int tid      = threadIdx.x;
    const int gid      = blockIdx.x * blockDim.x + tid;
    const int nthreads = gridDim.x * blockDim.x;
    const int npacks   = n >> 2;

    const float4* outs4 = (const float4*)outs;
    const int4*   tgt4  = (const int4*)tgt;

    // 8 samples / iteration; per-thread total 32 samples (2048x256 grid):
    // count field <= 32 < 64, q field <= 32*ln2*2^21 = 46.5M < 2^26. No overflow.
    int p = gid;
    for (; p + nthreads < npacks; p += 2 * nthreads) {
        int p2 = p + nthreads;
        float4 a0 = outs4[2 * p];
        float4 a1 = outs4[2 * p + 1];
        int4   t0 = tgt4[p];
        float4 b0 = outs4[2 * p2];
        float4 b1 = outs4[2 * p2 + 1];
        int4   t1 = tgt4[p2];
        proc4(a0, a1, t0, A);
        proc4(b0, b1, t1, A);
    }
    for (; p < npacks; p += nthreads) {
        float4 a0 = outs4[2 * p];
        float4 a1 = outs4[2 * p + 1];
        int4   t0 = tgt4[p];
        proc4(a0, a1, t0, A);
    }
    int tail = n & 3;
    if (gid < tail) {
        int s = (npacks << 2) + gid;
        proc1(outs[2 * s], outs[2 * s + 1], tgt[s], A);
    }

    // Epilogue (only LDS use in the kernel): dump packed regs, tree-reduce.
    __shared__ unsigned h[BINS][256];   // 10 KB
    __shared__ unsigned s_c[BINS][16];
    __shared__ float    s_q[BINS][16];
    #pragma unroll
    for (int b = 0; b < BINS; ++b) h[b][tid] = A[b];
    __syncthreads();

    if (tid < 16 * BINS) {
        int bin  = tid >> 4;
        int part = tid & 15;
        unsigned c = 0, q = 0;                  // q <= 16*46.5M = 744M < 2^32
        #pragma unroll
        for (int j = 0; j < 16; ++j) {
            unsigned v = h[bin][j * 16 + part];
            c += v >> CSHIFT;
            q += v & QMASK;
        }
        s_c[bin][part] = c;
        s_q[bin][part] = (float)q;
    }
    __syncthreads();
    if (tid < BINS) {
        unsigned c = 0; float q = 0.0f;
        #pragma unroll
        for (int j = 0; j < 16; ++j) { c += s_c[tid][j]; q += s_q[tid][j]; }
        if (c) {
            atomicAdd(&ws_c[tid], c);
            atomicAdd(&ws_q[tid], q * (1.0f / QSCALE));  // loss units
        }
    }
}

__global__ void ghm_final(const float*    __restrict__ ws_q,
                          const unsigned* __restrict__ ws_c,
                          const float*    __restrict__ acc_sum,
                          float* __restrict__ out) {
    if (threadIdx.x == 0) {
        float r = 0.0f;
        float    pq = 0.0f;
        unsigned pc = 0u;
        #pragma unroll
        for (int b = 0; b < BINS; ++b) {        // cumulative -> per-bin diff
            float    cq = ws_q[b];
            unsigned cc = ws_c[b];
            unsigned cnt = cc - pc;
            float    qs  = cq - pq;
            pc = cc; pq = cq;
            if (cnt > 0u) {
                float na = 0.75f * acc_sum[b] + 0.25f * (float)cnt;
                r += qs / na;    // = (1/N) * sum(loss_i * N/na[bin_i])
            }
        }
        *out = r;
    }
}

extern "C" void kernel_launch(void* const* d_in, const int* in_sizes, int n_in,
                              void* d_out, int out_size, void* d_ws, size_t ws_size,
                              hipStream_t stream) {
    const float* outputs = (const float*)d_in[0];  // [N,2] f32
    const int*   targets = (const int*)d_in[1];    // [N] int32
    const float* acc_sum = (const float*)d_in[2];  // [10] f32
    int n = in_sizes[1];

    float*    ws_q = (float*)d_ws;
    unsigned* ws_c = (unsigned*)((char*)d_ws + 64);

    ghm_zero_ws<<<1, 64, 0, stream>>>((unsigned*)d_ws);
    // 2048 blocks keeps per-thread sample count at 32 (packed-field headroom).
    ghm_main<<<2048, 256, 0, stream>>>(outputs, targets, ws_q, ws_c, n);
    ghm_final<<<1, 64, 0, stream>>>(ws_q, ws_c, acc_sum, (float*)d_out);
}